// Round 20
// baseline (139.674 us; speedup 1.0000x reference)
//
#include <hip/hip_runtime.h>
#include <hip/hip_bf16.h>

#define B_ 4
#define S_ 4096
#define E_ 1024
#define D_ 128

typedef unsigned short u16;
typedef __bf16 bf16x8 __attribute__((ext_vector_type(8)));
typedef unsigned short u16x8 __attribute__((ext_vector_type(8)));
typedef float f32x4 __attribute__((ext_vector_type(4)));

__device__ inline u16 f2bf(float f) {
    __bf16 h = (__bf16)f;
    return __builtin_bit_cast(u16, h);
}

// direct global->LDS DMA, 16B per lane, no VGPR round-trip
__device__ inline void gload16(const void* g, void* l) {
    __builtin_amdgcn_global_load_lds(
        (const __attribute__((address_space(1))) void*)g,
        (__attribute__((address_space(3))) void*)l, 16, 0, 0);
}

__device__ inline bf16x8 cvt8(float4 lo, float4 hi) {
    union { bf16x8 v; __bf16 e[8]; } a;
    a.e[0] = (__bf16)lo.x; a.e[1] = (__bf16)lo.y;
    a.e[2] = (__bf16)lo.z; a.e[3] = (__bf16)lo.w;
    a.e[4] = (__bf16)hi.x; a.e[5] = (__bf16)hi.y;
    a.e[6] = (__bf16)hi.z; a.e[7] = (__bf16)hi.w;
    return a.v;
}

// VALU-pipe (DPP) butterfly reductions over 16-lane rows.
__device__ inline float dpp_max16(float x) {
    int v = __builtin_bit_cast(int, x);
    x = fmaxf(x, __builtin_bit_cast(float, __builtin_amdgcn_update_dpp(0, v, 0xB1, 0xF, 0xF, true)));
    v = __builtin_bit_cast(int, x);
    x = fmaxf(x, __builtin_bit_cast(float, __builtin_amdgcn_update_dpp(0, v, 0x4E, 0xF, 0xF, true)));
    v = __builtin_bit_cast(int, x);
    x = fmaxf(x, __builtin_bit_cast(float, __builtin_amdgcn_update_dpp(0, v, 0x141, 0xF, 0xF, true)));
    v = __builtin_bit_cast(int, x);
    x = fmaxf(x, __builtin_bit_cast(float, __builtin_amdgcn_update_dpp(0, v, 0x140, 0xF, 0xF, true)));
    return x;
}
__device__ inline float dpp_add16(float x) {
    int v = __builtin_bit_cast(int, x);
    x += __builtin_bit_cast(float, __builtin_amdgcn_update_dpp(0, v, 0xB1, 0xF, 0xF, true));
    v = __builtin_bit_cast(int, x);
    x += __builtin_bit_cast(float, __builtin_amdgcn_update_dpp(0, v, 0x4E, 0xF, 0xF, true));
    v = __builtin_bit_cast(int, x);
    x += __builtin_bit_cast(float, __builtin_amdgcn_update_dpp(0, v, 0x141, 0xF, 0xF, true));
    v = __builtin_bit_cast(int, x);
    x += __builtin_bit_cast(float, __builtin_amdgcn_update_dpp(0, v, 0x140, 0xF, 0xF, true));
    return x;
}

// ---------------------------------------------------------------------------
// Kernel 0: W [E,D] f32 -> Wt2, the exact per-K-step LDS image (r16).
// ---------------------------------------------------------------------------
__global__ __launch_bounds__(256) void wt_kernel(const float* __restrict__ Wq,
                                                 const float* __restrict__ Wk,
                                                 const float* __restrict__ Wv,
                                                 u16* __restrict__ Wt) {
    int sid = blockIdx.x * 256 + threadIdx.x;   // 0 .. 49151 (16B slots)
    int l = sid & 63;
    int t8 = (sid >> 6) & 7;
    int ks = (sid >> 9) & 31;
    int w = sid >> 14;
    int g = l >> 4;
    int c = l & 15;
    int d = t8 * 16 + c;
    const float* W = (w == 0) ? Wq : ((w == 1) ? Wk : Wv);
    union { u16x8 v; u16 e[8]; } pk;
#pragma unroll
    for (int jj = 0; jj < 8; jj++) {
        int e = ks * 32 + g * 8 + jj;
        float v = W[(size_t)e * D_ + d];
        if (w == 0) v *= 0.08838834764831845f;   // 1/sqrt(128)
        pk.e[jj] = f2bf(v);
    }
    *(u16x8*)((char*)Wt + (size_t)sid * 16) = pk.v;
}

// ---------------------------------------------------------------------------
// Kernel 1: QKV LDS-staged GEMM, BK=64, counted-vmcnt, PHASE REORDERED:
// cvt (consume x loaded 2 phases ago) happens FIRST in each phase, BEFORE
// STAGE_W2 issues this phase's 6 W-loads. r19 diagnosis: any conservative
// compiler waitcnt before the cvt uses (inline-asm waitcnt interference,
// rule #18 family) would drag the just-issued W-stage (L2 ~300cyc) into
// every phase's critical path (16 x 300 ~= 2us). With cvt first, even a
// conservative wait only covers >=1-phase-old loads (already complete).
// ---------------------------------------------------------------------------
__global__ __launch_bounds__(512, 2) void qkv_fused(const float* __restrict__ x,
                                                    const u16* __restrict__ Wt,
                                                    u16* __restrict__ q,
                                                    u16* __restrict__ k,
                                                    u16* __restrict__ vT) {
    const int mrow0 = blockIdx.x * 64;
    const int wv = threadIdx.x >> 6;   // 0..7
    const int l = threadIdx.x & 63;
    const int g = l >> 4;
    const int c = l & 15;
    const int wr = wv >> 2;            // 0..1 (32-row half)
    const int wc = wv & 3;             // 0..3 (96-col group)

    __shared__ __align__(16) char wlds[2][48 * 1024];   // 96 KB dbuf (2 k-steps)

    // stage both k-steps (2*ph, 2*ph+1) of phase ph into buf: 6 x 1KB reads
    auto STAGE_W2 = [&](int buf, int ph) {
#pragma unroll
        for (int half = 0; half < 2; half++) {
            int ksIdx = ph * 2 + half;
#pragma unroll
            for (int ii = 0; ii < 3; ii++) {
                int ct = wv * 3 + ii;              // 0..23 ; w=ct>>3, t8=ct&7
                const char* gp = (const char*)Wt
                    + ((size_t)(((ct >> 3) * 32 + ksIdx) * 8 + (ct & 7)) * 1024) + l * 16;
                gload16(gp, wlds[buf] + half * 24576 + ct * 1024);
            }
        }
    };

    const float* xrow[2];
#pragma unroll
    for (int sub = 0; sub < 2; sub++)
        xrow[sub] = x + (size_t)(mrow0 + wr * 32 + sub * 16 + c) * E_ + g * 8;

    f32x4 acc[2][6] = {};

    auto MF2 = [&](int bufv, int half, bf16x8 av0, bf16x8 av1) {
#pragma unroll
        for (int ct = 0; ct < 6; ct++) {
            u16x8 braw = *(const u16x8*)(wlds[bufv] + half * 24576 + (wc * 6 + ct) * 1024 + l * 16);
            bf16x8 bw = __builtin_bit_cast(bf16x8, braw);
            acc[0][ct] = __builtin_amdgcn_mfma_f32_16x16x32_bf16(av0, bw, acc[0][ct], 0, 0, 0);
            acc[1][ct] = __builtin_amdgcn_mfma_f32_16x16x32_bf16(av1, bw, acc[1][ct], 0, 0, 0);
        }
    };

    // prologue: stage phase 0; x for phase 0 (slot A) and phase 1 (slot B)
    STAGE_W2(0, 0);
    __builtin_amdgcn_sched_barrier(0);
    float4 xa000 = *(const float4*)(xrow[0]);
    float4 xa001 = *(const float4*)(xrow[0] + 4);
    float4 xa010 = *(const float4*)(xrow[0] + 32);
    float4 xa011 = *(const float4*)(xrow[0] + 36);
    float4 xa100 = *(const float4*)(xrow[1]);
    float4 xa101 = *(const float4*)(xrow[1] + 4);
    float4 xa110 = *(const float4*)(xrow[1] + 32);
    float4 xa111 = *(const float4*)(xrow[1] + 36);
    float4 xb000 = *(const float4*)(xrow[0] + 64);
    float4 xb001 = *(const float4*)(xrow[0] + 68);
    float4 xb010 = *(const float4*)(xrow[0] + 96);
    float4 xb011 = *(const float4*)(xrow[0] + 100);
    float4 xb100 = *(const float4*)(xrow[1] + 64);
    float4 xb101 = *(const float4*)(xrow[1] + 68);
    float4 xb110 = *(const float4*)(xrow[1] + 96);
    float4 xb111 = *(const float4*)(xrow[1] + 100);
    asm volatile("s_waitcnt vmcnt(16)" ::: "memory");   // W(0) done; x in flight
    __builtin_amdgcn_s_barrier();

    int buf = 0;
    for (int it = 0; it < 8; it++) {
        // ---- even phase ph = 2*it (slot A): CONSUME x FIRST ----
        {
            bf16x8 av00 = cvt8(xa000, xa001), av01 = cvt8(xa010, xa011);
            bf16x8 av10 = cvt8(xa100, xa101), av11 = cvt8(xa110, xa111);
            STAGE_W2(buf ^ 1, 2 * it + 1);
            __builtin_amdgcn_sched_barrier(0);
            if (it < 7) {
                int f0 = (2 * it + 2) * 64;        // float offset of phase ph+2
                xa000 = *(const float4*)(xrow[0] + f0);
                xa001 = *(const float4*)(xrow[0] + f0 + 4);
                xa010 = *(const float4*)(xrow[0] + f0 + 32);
                xa011 = *(const float4*)(xrow[0] + f0 + 36);
                xa100 = *(const float4*)(xrow[1] + f0);
                xa101 = *(const float4*)(xrow[1] + f0 + 4);
                xa110 = *(const float4*)(xrow[1] + f0 + 32);
                xa111 = *(const float4*)(xrow[1] + f0 + 36);
            }
            MF2(buf, 0, av00, av10);
            MF2(buf, 1, av01, av11);
        }
        if (it < 7) asm volatile("s_waitcnt vmcnt(8) lgkmcnt(0)" ::: "memory");
        else        asm volatile("s_waitcnt vmcnt(0) lgkmcnt(0)" ::: "memory");
        __builtin_amdgcn_s_barrier();
        buf ^= 1;

        // ---- odd phase ph = 2*it+1 (slot B): CONSUME x FIRST ----
        {
            bf16x8 av00 = cvt8(xb000, xb001), av01 = cvt8(xb010, xb011);
            bf16x8 av10 = cvt8(xb100, xb101), av11 = cvt8(xb110, xb111);
            if (it < 7) STAGE_W2(buf ^ 1, 2 * it + 2);
            __builtin_amdgcn_sched_barrier(0);
            if (it < 7) {
                int f0 = (2 * it + 3) * 64;
                xb000 = *(const float4*)(xrow[0] + f0);
                xb001 = *(const float4*)(xrow[0] + f0 + 4);
                xb010 = *(const float4*)(xrow[0] + f0 + 32);
                xb011 = *(const float4*)(xrow[0] + f0 + 36);
                xb100 = *(const float4*)(xrow[1] + f0);
                xb101 = *(const float4*)(xrow[1] + f0 + 4);
                xb110 = *(const float4*)(xrow[1] + f0 + 32);
                xb111 = *(const float4*)(xrow[1] + f0 + 36);
            }
            MF2(buf, 0, av00, av10);
            MF2(buf, 1, av01, av11);
        }
        if (it < 7) {
            asm volatile("s_waitcnt vmcnt(8) lgkmcnt(0)" ::: "memory");
            __builtin_amdgcn_s_barrier();
            buf ^= 1;
        }
    }

    // ---- epilogue (registers only) ----
#pragma unroll
    for (int sub = 0; sub < 2; sub++) {
#pragma unroll
        for (int ct = 0; ct < 6; ct++) {
            int gc = (wc * 6 + ct) * 16;
            int proj = gc >> 7;
            int dcol = gc & 127;
            if (proj < 2) {
                u16* dst = proj ? k : q;
#pragma unroll
                for (int j = 0; j < 4; j++) {
                    int row = mrow0 + wr * 32 + sub * 16 + g * 4 + j;
                    dst[(size_t)row * D_ + dcol + c] = f2bf(acc[sub][ct][j]);
                }
            } else {
                int srow = mrow0 + wr * 32 + sub * 16 + g * 4;
                int b = srow >> 12;
                int s = srow & 4095;
                ushort4 pk;
                pk.x = f2bf(acc[sub][ct][0]);
                pk.y = f2bf(acc[sub][ct][1]);
                pk.z = f2bf(acc[sub][ct][2]);
                pk.w = f2bf(acc[sub][ct][3]);
                *(ushort4*)(vT + ((size_t)(b * D_ + dcol + c)) * S_ + s) = pk;
            }
        }
    }
}

// ---------------------------------------------------------------------------
// Kernel 2: flash attention — r14-EXACT (verified local optimum, 97.1-97.4us;
// r11/r17/r18 structural perturbations all regressed).
// ---------------------------------------------------------------------------
__global__ __launch_bounds__(512) void attn_kernel(const u16* __restrict__ q,
                                                   const u16* __restrict__ k,
                                                   const u16* __restrict__ vT,
                                                   float* __restrict__ out) {
    // bijective XCD-chunk swizzle (nwg=256, 8 XCDs, chunk=32)
    int bid = blockIdx.x;
    int sw = (bid & 7) * 32 + (bid >> 3);
    const int b = sw >> 6;          // batch 0..3 (2 XCDs per batch)
    const int qt = sw & 63;         // q-tile 0..63 (64 rows)
    const int wv = threadIdx.x >> 6;    // 0..7
    const int grp = wv >> 2;            // 0 = even tiles, 1 = odd tiles
    const int wq = wv & 3;              // q-subtile within block
    const int l = threadIdx.x & 63;
    const int g = l >> 4;
    const int c = l & 15;
    const int qrow0 = qt * 64 + wq * 16;   // within batch

    __shared__ __align__(16) char kv_lds[4 * 32768];   // 4 bufs (K 16K | V 16K)
    __shared__ __align__(16) u16 plds[8][1024];        // per-wave 2KB P buffer
    __shared__ float cmB[64], clB[64];
    u16* pw = &plds[wv][0];

    const char* kbb = (const char*)(k + (size_t)b * S_ * D_);
    const char* vbb = (const char*)(vT + (size_t)b * D_ * S_);

    // Q fragments, hoisted (scaled already, via Wq)
    bf16x8 aq[4];
    const u16* qp = q + ((size_t)(b * S_ + qrow0 + c)) * D_ + g * 8;
#pragma unroll
    for (int ks = 0; ks < 4; ks++) aq[ks] = *(const bf16x8*)(qp + ks * 32);

    f32x4 o[8] = {};
    float m[4], ll[4];
#pragma unroll
    for (int j = 0; j < 4; j++) { m[j] = -1e30f; ll[j] = 0.0f; }

    auto STAGE = [&](int buf, int kvbase) {
#pragma unroll
        for (int ii = 0; ii < 4; ii++) {           // K: [64][256B] rows
            int i = wq * 4 + ii;                   // instr 0..15, 1KB each
            int row = i * 4 + (l >> 4);
            int colb = (l & 15) * 16;
            const char* gp = kbb + (size_t)kvbase * 256 + (size_t)row * 256
                           + (colb ^ ((row & 7) << 4));
            gload16(gp, kv_lds + buf * 32768 + i * 1024);
        }
#pragma unroll
        for (int ii = 0; ii < 4; ii++) {           // V: [128][128B] rows
            int i = wq * 4 + ii;
            int row = i * 8 + (l >> 3);
            int colb = (l & 7) * 16;
            const char* gp = vbb + (size_t)row * 8192 + (size_t)kvbase * 2
                           + (colb ^ ((row & 7) << 4));
            gload16(gp, kv_lds + buf * 32768 + 16384 + i * 1024);
        }
    };

    STAGE(grp, grp * 64);
    __syncthreads();                 // drains vmcnt: bufs 0,1 ready
    const int swz = (c & 7) << 4;

    for (int t = 0; t < 32; t++) {
        const int mytile = 2 * t + grp;
        if (t < 31) STAGE((mytile + 2) & 3, (mytile + 2) * 64);

        const char* kbuf = kv_lds + (mytile & 3) * 32768;
        const char* vbuf = kbuf + 16384;

        // ---- S = Q K^T : 4 tiles of 16 kv-cols, K-dim 128 ----
        f32x4 s[4] = {};
        __builtin_amdgcn_s_setprio(1);
#pragma unroll
        for (int tt = 0; tt < 4; tt++) {
            int rb = (tt * 16 + c) * 256;
#pragma unroll
            for (int ks = 0; ks < 4; ks++) {
                u16x8 kr = *(const u16x8*)(kbuf + rb + ((ks * 64 + g * 16) ^ swz));
                bf16x8 bk = __builtin_bit_cast(bf16x8, kr);
                s[tt] = __builtin_amdgcn_mfma_f32_16x16x32_bf16(aq[ks], bk, s[tt], 0, 0, 0);
            }
        }
        __builtin_amdgcn_s_setprio(0);

        // ---- online softmax: DPP reduce + defer-max (THR=8) ----
        float tmj[4];
        bool need = false;
#pragma unroll
        for (int j = 0; j < 4; j++) {
            float tm = fmaxf(fmaxf(s[0][j], s[1][j]), fmaxf(s[2][j], s[3][j]));
            tm = dpp_max16(tm);
            tmj[j] = tm;
            need = need || (tm > m[j] + 8.0f);
        }
        if (__any(need)) {
#pragma unroll
            for (int j = 0; j < 4; j++) {
                float mn = fmaxf(m[j], tmj[j]);
                float alpha = exp2f((m[j] - mn) * 1.44269504f);
                ll[j] *= alpha;
#pragma unroll
                for (int ct = 0; ct < 8; ct++) o[ct][j] *= alpha;
                m[j] = mn;
            }
        }
        float pv[4][4];
#pragma unroll
        for (int j = 0; j < 4; j++) {
            float rs = 0.f;
#pragma unroll
            for (int tt = 0; tt < 4; tt++) {
                float p = exp2f((s[tt][j] - m[j]) * 1.44269504f);
                pv[tt][j] = p;
                rs += p;
            }
            ll[j] += dpp_add16(rs);
        }

        // ---- P -> LDS (wave-private), XOR-swizzled ----
#pragma unroll
        for (int tt = 0; tt < 4; tt++) {
#pragma unroll
            for (int j = 0; j < 4; j++) {
                int r = g * 4 + j;
                int cf = tt * 16 + c;
                int slot = (cf >> 3) ^ ((r & 7) ^ ((r & 8) >> 2));
                pw[r * 64 + slot * 8 + (cf & 7)] = f2bf(pv[tt][j]);
            }
        }

        // ---- PV: O += P[16,64] * V[64,128] ----
        __builtin_amdgcn_s_setprio(1);
#pragma unroll
        for (int st = 0; st < 2; st++) {
            int rho = c;
            int sigma = g + st * 4;
            int slot = sigma ^ ((rho & 7) ^ ((rho & 8) >> 2));
            u16x8 praw = *(const u16x8*)(pw + rho * 64 + slot * 8);
            bf16x8 pa = __builtin_bit_cast(bf16x8, praw);
#pragma unroll
            for (int ct = 0; ct < 8; ct++) {
                int rb = (ct * 16 + c) * 128;
                u16x8 vr = *(const u16x8*)(vbuf + rb + ((st * 64 + g * 16) ^ swz));
                bf16x8 bv = __builtin_bit_cast(bf16x8, vr);
                o[ct] = __builtin_amdgcn_mfma_f32_16x16x32_bf16(pa, bv, o[ct], 0, 0, 0);
            }
        }
        __builtin_amdgcn_s_setprio(0);

        __syncthreads();    // drain staging vmcnt + round barrier
    }

    // ---- 2-way merge: grp 1 -> LDS, grp 0 merges and stores ----
    float* co = (float*)kv_lds;     // 32KB, staging complete
    if (grp == 1) {
#pragma unroll
        for (int ct = 0; ct < 8; ct++) {
#pragma unroll
            for (int j = 0; j < 4; j++)
                co[(size_t)(wq * 16 + g * 4 + j) * 128 + ct * 16 + c] = o[ct][j];
        }
        if (c == 0) {
#pragma unroll
            for (int j = 0; j < 4; j++) {
                cmB[wq * 16 + g * 4 + j] = m[j];
                clB[wq * 16 + g * 4 + j] = ll[j];
            }
        }
    }
    __syncthreads();
    if (grp == 0) {
#pragma unroll
        for (int j = 0; j < 4; j++) {
            int r = wq * 16 + g * 4 + j;
            float mB = cmB[r], lB = clB[r];
            float M = fmaxf(m[j], mB);
            float eA = exp2f((m[j] - M) * 1.44269504f);
            float eB = exp2f((mB - M) * 1.44269504f);
            float rL = 1.0f / (ll[j] * eA + lB * eB);
            float* op = out + ((size_t)(b * S_ + qt * 64 + r)) * D_;
#pragma unroll
            for (int ct = 0; ct < 8; ct++) {
                op[ct * 16 + c] = (o[ct][j] * eA + co[(size_t)r * 128 + ct * 16 + c] * eB) * rL;
            }
        }
    }
}

extern "C" void kernel_launch(void* const* d_in, const int* in_sizes, int n_in,
                              void* d_out, int out_size, void* d_ws, size_t ws_size,
                              hipStream_t stream) {
    const float* x  = (const float*)d_in[0];
    const float* Wq = (const float*)d_in[1];
    const float* Wk = (const float*)d_in[2];
    const float* Wv = (const float*)d_in[3];
    float* out = (float*)d_out;   // reference output dtype is float32

    // workspace layout (bytes): q 4MB | k 4MB | vT 4MB | Wt2 768KB
    u16* q  = (u16*)d_ws;
    u16* k  = q  + (size_t)B_ * S_ * D_;
    u16* vT = k  + (size_t)B_ * S_ * D_;
    u16* Wt = vT + (size_t)B_ * S_ * D_;

    wt_kernel<<<(3 * 32 * 8 * 64) / 256, 256, 0, stream>>>(Wq, Wk, Wv, Wt);
    qkv_fused<<<(B_ * S_) / 64, 512, 0, stream>>>(x, Wt, q, k, vT);
    attn_kernel<<<(B_ * S_) / 64, 512, 0, stream>>>(q, k, vT, out);
}

// Round 22
// 112.344 us; speedup vs baseline: 1.2433x; 1.2433x over previous
//
#include <hip/hip_runtime.h>
#include <hip/hip_bf16.h>

#define B_ 4
#define S_ 4096
#define E_ 1024
#define D_ 128

typedef unsigned short u16;
typedef unsigned int u32;
typedef __bf16 bf16x8 __attribute__((ext_vector_type(8)));
typedef unsigned short u16x8 __attribute__((ext_vector_type(8)));
typedef float f32x4 __attribute__((ext_vector_type(4)));
typedef float f32x16 __attribute__((ext_vector_type(16)));
typedef unsigned int u32x2 __attribute__((ext_vector_type(2)));
typedef unsigned int u32x4 __attribute__((ext_vector_type(4)));

__device__ inline u16 f2bf(float f) {
    __bf16 h = (__bf16)f;
    return __builtin_bit_cast(u16, h);
}

// direct global->LDS DMA, 16B per lane, no VGPR round-trip
__device__ inline void gload16(const void* g, void* l) {
    __builtin_amdgcn_global_load_lds(
        (const __attribute__((address_space(1))) void*)g,
        (__attribute__((address_space(3))) void*)l, 16, 0, 0);
}

__device__ inline bf16x8 cvt8(float4 lo, float4 hi) {
    union { bf16x8 v; __bf16 e[8]; } a;
    a.e[0] = (__bf16)lo.x; a.e[1] = (__bf16)lo.y;
    a.e[2] = (__bf16)lo.z; a.e[3] = (__bf16)lo.w;
    a.e[4] = (__bf16)hi.x; a.e[5] = (__bf16)hi.y;
    a.e[6] = (__bf16)hi.z; a.e[7] = (__bf16)hi.w;
    return a.v;
}

// v_permlane32_swap via BUILTIN (r21 bug: raw asm with "+v"(a),"+v"(b) where
// b==a let the compiler coalesce a,b into ONE register -> degenerate
// self-swap -> partner_max/sum silently wrong; builtin returns both results
// and models hazards).  r[0] = {a.lo | b.lo->hi}, r[1] = {a.hi->lo | b.hi}.
__device__ inline u32x2 plswap2(u32 a, u32 b) {
    return __builtin_amdgcn_permlane32_swap(a, b, false, false);
}
__device__ inline float partner_max(float x) {
    u32 v = __builtin_bit_cast(u32, x);
    u32x2 r = plswap2(v, v);
    return fmaxf(__builtin_bit_cast(float, r[0]), __builtin_bit_cast(float, r[1]));
}
__device__ inline float partner_sum(float x) {
    u32 v = __builtin_bit_cast(u32, x);
    u32x2 r = plswap2(v, v);
    return __builtin_bit_cast(float, r[0]) + __builtin_bit_cast(float, r[1]);
}
// packed bf16 pair via scalar casts (m240: compiler codegen beats asm cvt_pk)
__device__ inline u32 cvtpk(float lo, float hi) {
    return (u32)f2bf(lo) | ((u32)f2bf(hi) << 16);
}

// ---------------------------------------------------------------------------
// Kernel 0: W [E,D] f32 -> Wt2, the exact per-K-step LDS image (r16).
// ---------------------------------------------------------------------------
__global__ __launch_bounds__(256) void wt_kernel(const float* __restrict__ Wq,
                                                 const float* __restrict__ Wk,
                                                 const float* __restrict__ Wv,
                                                 u16* __restrict__ Wt) {
    int sid = blockIdx.x * 256 + threadIdx.x;   // 0 .. 49151 (16B slots)
    int l = sid & 63;
    int t8 = (sid >> 6) & 7;
    int ks = (sid >> 9) & 31;
    int w = sid >> 14;
    int g = l >> 4;
    int c = l & 15;
    int d = t8 * 16 + c;
    const float* W = (w == 0) ? Wq : ((w == 1) ? Wk : Wv);
    union { u16x8 v; u16 e[8]; } pk;
#pragma unroll
    for (int jj = 0; jj < 8; jj++) {
        int e = ks * 32 + g * 8 + jj;
        float v = W[(size_t)e * D_ + d];
        if (w == 0) v *= 0.08838834764831845f;   // 1/sqrt(128)
        pk.e[jj] = f2bf(v);
    }
    *(u16x8*)((char*)Wt + (size_t)sid * 16) = pk.v;
}

// ---------------------------------------------------------------------------
// Kernel 1: QKV LDS-staged GEMM, BK=64, counted-vmcnt (r20 form, ~33us).
// ---------------------------------------------------------------------------
__global__ __launch_bounds__(512, 2) void qkv_fused(const float* __restrict__ x,
                                                    const u16* __restrict__ Wt,
                                                    u16* __restrict__ q,
                                                    u16* __restrict__ k,
                                                    u16* __restrict__ vT) {
    const int mrow0 = blockIdx.x * 64;
    const int wv = threadIdx.x >> 6;   // 0..7
    const int l = threadIdx.x & 63;
    const int g = l >> 4;
    const int c = l & 15;
    const int wr = wv >> 2;            // 0..1 (32-row half)
    const int wc = wv & 3;             // 0..3 (96-col group)

    __shared__ __align__(16) char wlds[2][48 * 1024];   // 96 KB dbuf (2 k-steps)

    auto STAGE_W2 = [&](int buf, int ph) {
#pragma unroll
        for (int half = 0; half < 2; half++) {
            int ksIdx = ph * 2 + half;
#pragma unroll
            for (int ii = 0; ii < 3; ii++) {
                int ct = wv * 3 + ii;              // 0..23 ; w=ct>>3, t8=ct&7
                const char* gp = (const char*)Wt
                    + ((size_t)(((ct >> 3) * 32 + ksIdx) * 8 + (ct & 7)) * 1024) + l * 16;
                gload16(gp, wlds[buf] + half * 24576 + ct * 1024);
            }
        }
    };

    const float* xrow[2];
#pragma unroll
    for (int sub = 0; sub < 2; sub++)
        xrow[sub] = x + (size_t)(mrow0 + wr * 32 + sub * 16 + c) * E_ + g * 8;

    f32x4 acc[2][6] = {};

    auto MF2 = [&](int bufv, int half, bf16x8 av0, bf16x8 av1) {
#pragma unroll
        for (int ct = 0; ct < 6; ct++) {
            u16x8 braw = *(const u16x8*)(wlds[bufv] + half * 24576 + (wc * 6 + ct) * 1024 + l * 16);
            bf16x8 bw = __builtin_bit_cast(bf16x8, braw);
            acc[0][ct] = __builtin_amdgcn_mfma_f32_16x16x32_bf16(av0, bw, acc[0][ct], 0, 0, 0);
            acc[1][ct] = __builtin_amdgcn_mfma_f32_16x16x32_bf16(av1, bw, acc[1][ct], 0, 0, 0);
        }
    };

    STAGE_W2(0, 0);
    __builtin_amdgcn_sched_barrier(0);
    float4 xa000 = *(const float4*)(xrow[0]);
    float4 xa001 = *(const float4*)(xrow[0] + 4);
    float4 xa010 = *(const float4*)(xrow[0] + 32);
    float4 xa011 = *(const float4*)(xrow[0] + 36);
    float4 xa100 = *(const float4*)(xrow[1]);
    float4 xa101 = *(const float4*)(xrow[1] + 4);
    float4 xa110 = *(const float4*)(xrow[1] + 32);
    float4 xa111 = *(const float4*)(xrow[1] + 36);
    float4 xb000 = *(const float4*)(xrow[0] + 64);
    float4 xb001 = *(const float4*)(xrow[0] + 68);
    float4 xb010 = *(const float4*)(xrow[0] + 96);
    float4 xb011 = *(const float4*)(xrow[0] + 100);
    float4 xb100 = *(const float4*)(xrow[1] + 64);
    float4 xb101 = *(const float4*)(xrow[1] + 68);
    float4 xb110 = *(const float4*)(xrow[1] + 96);
    float4 xb111 = *(const float4*)(xrow[1] + 100);
    asm volatile("s_waitcnt vmcnt(16)" ::: "memory");   // W(0) done; x in flight
    __builtin_amdgcn_s_barrier();

    int buf = 0;
    for (int it = 0; it < 8; it++) {
        {
            bf16x8 av00 = cvt8(xa000, xa001), av01 = cvt8(xa010, xa011);
            bf16x8 av10 = cvt8(xa100, xa101), av11 = cvt8(xa110, xa111);
            STAGE_W2(buf ^ 1, 2 * it + 1);
            __builtin_amdgcn_sched_barrier(0);
            if (it < 7) {
                int f0 = (2 * it + 2) * 64;
                xa000 = *(const float4*)(xrow[0] + f0);
                xa001 = *(const float4*)(xrow[0] + f0 + 4);
                xa010 = *(const float4*)(xrow[0] + f0 + 32);
                xa011 = *(const float4*)(xrow[0] + f0 + 36);
                xa100 = *(const float4*)(xrow[1] + f0);
                xa101 = *(const float4*)(xrow[1] + f0 + 4);
                xa110 = *(const float4*)(xrow[1] + f0 + 32);
                xa111 = *(const float4*)(xrow[1] + f0 + 36);
            }
            MF2(buf, 0, av00, av10);
            MF2(buf, 1, av01, av11);
        }
        if (it < 7) asm volatile("s_waitcnt vmcnt(8) lgkmcnt(0)" ::: "memory");
        else        asm volatile("s_waitcnt vmcnt(0) lgkmcnt(0)" ::: "memory");
        __builtin_amdgcn_s_barrier();
        buf ^= 1;

        {
            bf16x8 av00 = cvt8(xb000, xb001), av01 = cvt8(xb010, xb011);
            bf16x8 av10 = cvt8(xb100, xb101), av11 = cvt8(xb110, xb111);
            if (it < 7) STAGE_W2(buf ^ 1, 2 * it + 2);
            __builtin_amdgcn_sched_barrier(0);
            if (it < 7) {
                int f0 = (2 * it + 3) * 64;
                xb000 = *(const float4*)(xrow[0] + f0);
                xb001 = *(const float4*)(xrow[0] + f0 + 4);
                xb010 = *(const float4*)(xrow[0] + f0 + 32);
                xb011 = *(const float4*)(xrow[0] + f0 + 36);
                xb100 = *(const float4*)(xrow[1] + f0);
                xb101 = *(const float4*)(xrow[1] + f0 + 4);
                xb110 = *(const float4*)(xrow[1] + f0 + 32);
                xb111 = *(const float4*)(xrow[1] + f0 + 36);
            }
            MF2(buf, 0, av00, av10);
            MF2(buf, 1, av01, av11);
        }
        if (it < 7) {
            asm volatile("s_waitcnt vmcnt(8) lgkmcnt(0)" ::: "memory");
            __builtin_amdgcn_s_barrier();
            buf ^= 1;
        }
    }

#pragma unroll
    for (int sub = 0; sub < 2; sub++) {
#pragma unroll
        for (int ct = 0; ct < 6; ct++) {
            int gc = (wc * 6 + ct) * 16;
            int proj = gc >> 7;
            int dcol = gc & 127;
            if (proj < 2) {
                u16* dst = proj ? k : q;
#pragma unroll
                for (int j = 0; j < 4; j++) {
                    int row = mrow0 + wr * 32 + sub * 16 + g * 4 + j;
                    dst[(size_t)row * D_ + dcol + c] = f2bf(acc[sub][ct][j]);
                }
            } else {
                int srow = mrow0 + wr * 32 + sub * 16 + g * 4;
                int b = srow >> 12;
                int s = srow & 4095;
                ushort4 pk;
                pk.x = f2bf(acc[sub][ct][0]);
                pk.y = f2bf(acc[sub][ct][1]);
                pk.z = f2bf(acc[sub][ct][2]);
                pk.w = f2bf(acc[sub][ct][3]);
                *(ushort4*)(vT + ((size_t)(b * D_ + dcol + c)) * S_ + s) = pk;
            }
        }
    }
}

// ---------------------------------------------------------------------------
// Kernel 2: flash attention, SWAPPED 32x32 structure (T12) — r21 layout
// (all fragment mappings re-verified) with the plswap helpers fixed to use
// __builtin_amdgcn_permlane32_swap (r21's raw asm coalesced its two
// operands when they held the same value -> degenerate swap -> m
// inconsistent across partner lanes + llF = 2*ll_partner -> absmax 1.3e-2).
// ---------------------------------------------------------------------------
__global__ __launch_bounds__(512, 2) void attn_kernel(const u16* __restrict__ q,
                                                      const u16* __restrict__ k,
                                                      const u16* __restrict__ vT,
                                                      float* __restrict__ out) {
    // bijective XCD-chunk swizzle (nwg=256, 8 XCDs, chunk=32)
    int bid = blockIdx.x;
    int sw = (bid & 7) * 32 + (bid >> 3);
    const int b = sw >> 6;          // batch 0..3 (2 XCDs per batch)
    const int qt = sw & 63;         // q-tile 0..63 (64 rows)
    const int wv = threadIdx.x >> 6;    // 0..7
    const int qs = wv >> 2;             // q-sub 0..1 (32 rows)
    const int grp = wv & 3;             // kv group: tiles t*4+grp
    const int l = threadIdx.x & 63;
    const int l31 = l & 31;
    const int hi = l >> 5;
    const int qrow = qt * 64 + qs * 32 + l31;   // this lane's q (within batch)

    __shared__ __align__(16) char smem[134400];
    char* gbase = smem + grp * 32768;

    const char* kbb = (const char*)(k + (size_t)b * S_ * D_);
    const char* vbb = (const char*)(vT + (size_t)b * D_ * S_);

    // Q B-frags: B[k=e][col=q]; lane: q=qrow, e = ek*16 + hi*8 + j
    bf16x8 aq[8];
    const u16* qp = q + (size_t)(b * S_ + qrow) * D_ + hi * 8;
#pragma unroll
    for (int ek = 0; ek < 8; ek++) aq[ek] = *(const bf16x8*)(qp + ek * 16);

    f32x16 o[4] = {};   // o[dt][r] = O^T[d=dt*32+crow(r,hi)][q=qrow]
    float m = -1e30f, ll = 0.0f;   // ll: partial (own crow half)

    auto STAGE = [&](int buf, int kvbase) {
        char* dst = gbase + buf * 16384;
#pragma unroll
        for (int ii = 0; ii < 4; ii++) {           // K rows, 1KB each
            int i = qs * 4 + ii;                   // 0..7
            int row = i * 4 + (l >> 4);            // 0..31
            int colb = (l & 15) * 16;
            const char* gp = kbb + (size_t)(kvbase + row) * 256
                           + (colb ^ ((row & 7) << 4));
            gload16(gp, dst + i * 1024);
        }
#pragma unroll
        for (int ii = 0; ii < 4; ii++) {           // V d-rows (64B each)
            int i = qs * 4 + ii;
            int row = i * 16 + (l >> 2);           // 0..127
            int colb = (l & 3) * 16;
            const char* gp = vbb + (size_t)row * 8192 + (size_t)kvbase * 2
                           + (colb ^ ((row & 3) << 4));
            gload16(gp, dst + 8192 + i * 1024);
        }
    };

    STAGE(0, grp * 32);
    __syncthreads();                 // drains vmcnt: buf0 ready

    int buf = 0;
    for (int t = 0; t < 32; t++) {
        const int kvbase = (t * 4 + grp) * 32;
        if (t < 31) STAGE(buf ^ 1, kvbase + 128);

        const char* kbuf = gbase + buf * 16384;
        const char* vbuf = kbuf + 8192;

        // ---- S^T = K Q^T : 8 x mfma 32x32x16 over e ----
        f32x16 s = {};
        __builtin_amdgcn_s_setprio(1);
#pragma unroll
        for (int ek = 0; ek < 8; ek++) {
            u16x8 kr = *(const u16x8*)(kbuf + l31 * 256
                       + ((ek * 32 + hi * 16) ^ ((l31 & 7) << 4)));
            s = __builtin_amdgcn_mfma_f32_32x32x16_bf16(
                    __builtin_bit_cast(bf16x8, kr), aq[ek], s, 0, 0, 0);
        }
        __builtin_amdgcn_s_setprio(0);

        // ---- in-register softmax (lane owns q=qrow; 16 of 32 kv) ----
        float tm = s[0];
#pragma unroll
        for (int r = 1; r < 16; r++) tm = fmaxf(tm, s[r]);
        float tilemax = partner_max(tm);
        bool need = tilemax > m + 8.0f;
        if (__any(need)) {
            float mn = fmaxf(m, tilemax);
            float alpha = exp2f((m - mn) * 1.44269504f);
            ll *= alpha;
#pragma unroll
            for (int dt = 0; dt < 4; dt++)
#pragma unroll
                for (int r = 0; r < 16; r++) o[dt][r] *= alpha;
            m = mn;
        }
        float p[16];
        float rs = 0.f;
#pragma unroll
        for (int r = 0; r < 16; r++) {
            p[r] = exp2f((s[r] - m) * 1.44269504f);
            rs += p[r];
        }
        ll += rs;

        // ---- pack P^T frags: 8 packs + 4 permlane32_swap ----
        u32 c0 = cvtpk(p[0], p[1]),  c1 = cvtpk(p[2], p[3]);
        u32 c2 = cvtpk(p[4], p[5]),  c3 = cvtpk(p[6], p[7]);
        u32 c4 = cvtpk(p[8], p[9]),  c5 = cvtpk(p[10], p[11]);
        u32 c6 = cvtpk(p[12], p[13]), c7 = cvtpk(p[14], p[15]);
        { u32x2 r = plswap2(c0, c2); c0 = r[0]; c2 = r[1]; }
        { u32x2 r = plswap2(c1, c3); c1 = r[0]; c3 = r[1]; }
        { u32x2 r = plswap2(c4, c6); c4 = r[0]; c6 = r[1]; }
        { u32x2 r = plswap2(c5, c7); c5 = r[0]; c7 = r[1]; }
        u32x4 f0v = {c0, c1, c2, c3};
        u32x4 f1v = {c4, c5, c6, c7};
        bf16x8 pb0 = __builtin_bit_cast(bf16x8, f0v);
        bf16x8 pb1 = __builtin_bit_cast(bf16x8, f1v);

        // ---- PV: o[dt] += V^T_frag x P^T_frag (2 kv-halves x 4 d-tiles) ----
        __builtin_amdgcn_s_setprio(1);
#pragma unroll
        for (int dt = 0; dt < 4; dt++) {
            int row = dt * 32 + l31;
            int swzv = (row & 3) << 4;
            u16x8 v0 = *(const u16x8*)(vbuf + row * 64 + ((hi * 16) ^ swzv));
            o[dt] = __builtin_amdgcn_mfma_f32_32x32x16_bf16(
                        __builtin_bit_cast(bf16x8, v0), pb0, o[dt], 0, 0, 0);
            u16x8 v1 = *(const u16x8*)(vbuf + row * 64 + ((32 + hi * 16) ^ swzv));
            o[dt] = __builtin_amdgcn_mfma_f32_32x32x16_bf16(
                        __builtin_bit_cast(bf16x8, v1), pb1, o[dt], 0, 0, 0);
        }
        __builtin_amdgcn_s_setprio(0);

        __syncthreads();    // drain staging vmcnt + round barrier
        buf ^= 1;
    }

    // ---- epilogue: transpose via LDS overlay + 4-way merge ----
    float llF = partner_sum(ll);    // combine the two kv-halves
    __syncthreads();                // kv bufs done; begin overlay
    float* co = (float*)smem;                 // [grp*64+q][129]
    float* cm = (float*)(smem + 132096);      // [4][64]
    float* cl = cm + 256;
    const int qloc = qs * 32 + l31;
#pragma unroll
    for (int dt = 0; dt < 4; dt++)
#pragma unroll
        for (int r = 0; r < 16; r++) {
            int d = dt * 32 + (r & 3) + 8 * (r >> 2) + 4 * hi;
            co[(size_t)(grp * 64 + qloc) * 129 + d] = o[dt][r];
        }
    cm[grp * 64 + qloc] = m;        // lanes l, l^32 write same value
    cl[grp * 64 + qloc] = llF;
    __syncthreads();

    {   // final: thread -> (q = tid>>3, 16 d at (tid&7)*16)
        int qq = (int)threadIdx.x >> 3;
        int dbase = ((int)threadIdx.x & 7) * 16;
        float M = cm[qq];
#pragma unroll
        for (int gi = 1; gi < 4; gi++) M = fmaxf(M, cm[gi * 64 + qq]);
        float eg[4];
        float L = 0.f;
#pragma unroll
        for (int gi = 0; gi < 4; gi++) {
            eg[gi] = exp2f((cm[gi * 64 + qq] - M) * 1.44269504f);
            L += cl[gi * 64 + qq] * eg[gi];
        }
        float rL = 1.0f / L;
        float* op = out + (size_t)(b * S_ + qt * 64 + qq) * D_ + dbase;
#pragma unroll
        for (int dd = 0; dd < 16; dd += 4) {
            float4 res;
#pragma unroll
            for (int i = 0; i < 4; i++) {
                float a = 0.f;
#pragma unroll
                for (int gi = 0; gi < 4; gi++)
                    a += co[(size_t)(gi * 64 + qq) * 129 + dbase + dd + i] * eg[gi];
                (&res.x)[i] = a * rL;
            }
            *(float4*)(op + dd) = res;
        }
    }
}

extern "C" void kernel_launch(void* const* d_in, const int* in_sizes, int n_in,
                              void* d_out, int out_size, void* d_ws, size_t ws_size,
                              hipStream_t stream) {
    const float* x  = (const float*)d_in[0];
    const float* Wq = (const float*)d_in[1];
    const float* Wk = (const float*)d_in[2];
    const float* Wv = (const float*)d_in[3];
    float* out = (float*)d_out;   // reference output dtype is float32

    // workspace layout (bytes): q 4MB | k 4MB | vT 4MB | Wt2 768KB
    u16* q  = (u16*)d_ws;
    u16* k  = q  + (size_t)B_ * S_ * D_;
    u16* vT = k  + (size_t)B_ * S_ * D_;
    u16* Wt = vT + (size_t)B_ * S_ * D_;

    wt_kernel<<<(3 * 32 * 8 * 64) / 256, 256, 0, stream>>>(Wq, Wk, Wv, Wt);
    qkv_fused<<<(B_ * S_) / 64, 512, 0, stream>>>(x, Wt, q, k, vT);
    attn_kernel<<<(B_ * S_) / 64, 512, 0, stream>>>(q, k, vT, out);
}

// Round 23
// 109.845 us; speedup vs baseline: 1.2716x; 1.0227x over previous
//
#include <hip/hip_runtime.h>
#include <hip/hip_bf16.h>

#define B_ 4
#define S_ 4096
#define E_ 1024
#define D_ 128

typedef unsigned short u16;
typedef unsigned int u32;
typedef __bf16 bf16x8 __attribute__((ext_vector_type(8)));
typedef unsigned short u16x8 __attribute__((ext_vector_type(8)));
typedef float f32x4 __attribute__((ext_vector_type(4)));
typedef float f32x16 __attribute__((ext_vector_type(16)));
typedef unsigned int u32x2 __attribute__((ext_vector_type(2)));
typedef unsigned int u32x4 __attribute__((ext_vector_type(4)));

__device__ inline u16 f2bf(float f) {
    __bf16 h = (__bf16)f;
    return __builtin_bit_cast(u16, h);
}

// direct global->LDS DMA, 16B per lane, no VGPR round-trip
__device__ inline void gload16(const void* g, void* l) {
    __builtin_amdgcn_global_load_lds(
        (const __attribute__((address_space(1))) void*)g,
        (__attribute__((address_space(3))) void*)l, 16, 0, 0);
}

__device__ inline bf16x8 cvt8(float4 lo, float4 hi) {
    union { bf16x8 v; __bf16 e[8]; } a;
    a.e[0] = (__bf16)lo.x; a.e[1] = (__bf16)lo.y;
    a.e[2] = (__bf16)lo.z; a.e[3] = (__bf16)lo.w;
    a.e[4] = (__bf16)hi.x; a.e[5] = (__bf16)hi.y;
    a.e[6] = (__bf16)hi.z; a.e[7] = (__bf16)hi.w;
    return a.v;
}

// v_permlane32_swap via builtin (r21 lesson: raw asm coalesced same-value
// operands into one register -> degenerate swap).
__device__ inline u32x2 plswap2(u32 a, u32 b) {
    return __builtin_amdgcn_permlane32_swap(a, b, false, false);
}
__device__ inline float partner_max(float x) {
    u32 v = __builtin_bit_cast(u32, x);
    u32x2 r = plswap2(v, v);
    return fmaxf(__builtin_bit_cast(float, r[0]), __builtin_bit_cast(float, r[1]));
}
__device__ inline float partner_sum(float x) {
    u32 v = __builtin_bit_cast(u32, x);
    u32x2 r = plswap2(v, v);
    return __builtin_bit_cast(float, r[0]) + __builtin_bit_cast(float, r[1]);
}
__device__ inline u32 cvtpk(float lo, float hi) {
    return (u32)f2bf(lo) | ((u32)f2bf(hi) << 16);
}

// ---------------------------------------------------------------------------
// Kernel 0: W [E,D] f32 -> Wt2, the exact per-K-step LDS image (r16).
// ---------------------------------------------------------------------------
__global__ __launch_bounds__(256) void wt_kernel(const float* __restrict__ Wq,
                                                 const float* __restrict__ Wk,
                                                 const float* __restrict__ Wv,
                                                 u16* __restrict__ Wt) {
    int sid = blockIdx.x * 256 + threadIdx.x;   // 0 .. 49151 (16B slots)
    int l = sid & 63;
    int t8 = (sid >> 6) & 7;
    int ks = (sid >> 9) & 31;
    int w = sid >> 14;
    int g = l >> 4;
    int c = l & 15;
    int d = t8 * 16 + c;
    const float* W = (w == 0) ? Wq : ((w == 1) ? Wk : Wv);
    union { u16x8 v; u16 e[8]; } pk;
#pragma unroll
    for (int jj = 0; jj < 8; jj++) {
        int e = ks * 32 + g * 8 + jj;
        float v = W[(size_t)e * D_ + d];
        if (w == 0) v *= 0.08838834764831845f;   // 1/sqrt(128)
        pk.e[jj] = f2bf(v);
    }
    *(u16x8*)((char*)Wt + (size_t)sid * 16) = pk.v;
}

// ---------------------------------------------------------------------------
// Kernel 1: QKV LDS-staged GEMM, BK=64, counted-vmcnt (r20 form, ~33us).
// FROZEN (r19/r20 falsified the remaining latency theories).
// ---------------------------------------------------------------------------
__global__ __launch_bounds__(512, 2) void qkv_fused(const float* __restrict__ x,
                                                    const u16* __restrict__ Wt,
                                                    u16* __restrict__ q,
                                                    u16* __restrict__ k,
                                                    u16* __restrict__ vT) {
    const int mrow0 = blockIdx.x * 64;
    const int wv = threadIdx.x >> 6;   // 0..7
    const int l = threadIdx.x & 63;
    const int g = l >> 4;
    const int c = l & 15;
    const int wr = wv >> 2;            // 0..1 (32-row half)
    const int wc = wv & 3;             // 0..3 (96-col group)

    __shared__ __align__(16) char wlds[2][48 * 1024];   // 96 KB dbuf (2 k-steps)

    auto STAGE_W2 = [&](int buf, int ph) {
#pragma unroll
        for (int half = 0; half < 2; half++) {
            int ksIdx = ph * 2 + half;
#pragma unroll
            for (int ii = 0; ii < 3; ii++) {
                int ct = wv * 3 + ii;              // 0..23 ; w=ct>>3, t8=ct&7
                const char* gp = (const char*)Wt
                    + ((size_t)(((ct >> 3) * 32 + ksIdx) * 8 + (ct & 7)) * 1024) + l * 16;
                gload16(gp, wlds[buf] + half * 24576 + ct * 1024);
            }
        }
    };

    const float* xrow[2];
#pragma unroll
    for (int sub = 0; sub < 2; sub++)
        xrow[sub] = x + (size_t)(mrow0 + wr * 32 + sub * 16 + c) * E_ + g * 8;

    f32x4 acc[2][6] = {};

    auto MF2 = [&](int bufv, int half, bf16x8 av0, bf16x8 av1) {
#pragma unroll
        for (int ct = 0; ct < 6; ct++) {
            u16x8 braw = *(const u16x8*)(wlds[bufv] + half * 24576 + (wc * 6 + ct) * 1024 + l * 16);
            bf16x8 bw = __builtin_bit_cast(bf16x8, braw);
            acc[0][ct] = __builtin_amdgcn_mfma_f32_16x16x32_bf16(av0, bw, acc[0][ct], 0, 0, 0);
            acc[1][ct] = __builtin_amdgcn_mfma_f32_16x16x32_bf16(av1, bw, acc[1][ct], 0, 0, 0);
        }
    };

    STAGE_W2(0, 0);
    __builtin_amdgcn_sched_barrier(0);
    float4 xa000 = *(const float4*)(xrow[0]);
    float4 xa001 = *(const float4*)(xrow[0] + 4);
    float4 xa010 = *(const float4*)(xrow[0] + 32);
    float4 xa011 = *(const float4*)(xrow[0] + 36);
    float4 xa100 = *(const float4*)(xrow[1]);
    float4 xa101 = *(const float4*)(xrow[1] + 4);
    float4 xa110 = *(const float4*)(xrow[1] + 32);
    float4 xa111 = *(const float4*)(xrow[1] + 36);
    float4 xb000 = *(const float4*)(xrow[0] + 64);
    float4 xb001 = *(const float4*)(xrow[0] + 68);
    float4 xb010 = *(const float4*)(xrow[0] + 96);
    float4 xb011 = *(const float4*)(xrow[0] + 100);
    float4 xb100 = *(const float4*)(xrow[1] + 64);
    float4 xb101 = *(const float4*)(xrow[1] + 68);
    float4 xb110 = *(const float4*)(xrow[1] + 96);
    float4 xb111 = *(const float4*)(xrow[1] + 100);
    asm volatile("s_waitcnt vmcnt(16)" ::: "memory");   // W(0) done; x in flight
    __builtin_amdgcn_s_barrier();

    int buf = 0;
    for (int it = 0; it < 8; it++) {
        {
            bf16x8 av00 = cvt8(xa000, xa001), av01 = cvt8(xa010, xa011);
            bf16x8 av10 = cvt8(xa100, xa101), av11 = cvt8(xa110, xa111);
            STAGE_W2(buf ^ 1, 2 * it + 1);
            __builtin_amdgcn_sched_barrier(0);
            if (it < 7) {
                int f0 = (2 * it + 2) * 64;
                xa000 = *(const float4*)(xrow[0] + f0);
                xa001 = *(const float4*)(xrow[0] + f0 + 4);
                xa010 = *(const float4*)(xrow[0] + f0 + 32);
                xa011 = *(const float4*)(xrow[0] + f0 + 36);
                xa100 = *(const float4*)(xrow[1] + f0);
                xa101 = *(const float4*)(xrow[1] + f0 + 4);
                xa110 = *(const float4*)(xrow[1] + f0 + 32);
                xa111 = *(const float4*)(xrow[1] + f0 + 36);
            }
            MF2(buf, 0, av00, av10);
            MF2(buf, 1, av01, av11);
        }
        if (it < 7) asm volatile("s_waitcnt vmcnt(8) lgkmcnt(0)" ::: "memory");
        else        asm volatile("s_waitcnt vmcnt(0) lgkmcnt(0)" ::: "memory");
        __builtin_amdgcn_s_barrier();
        buf ^= 1;

        {
            bf16x8 av00 = cvt8(xb000, xb001), av01 = cvt8(xb010, xb011);
            bf16x8 av10 = cvt8(xb100, xb101), av11 = cvt8(xb110, xb111);
            if (it < 7) STAGE_W2(buf ^ 1, 2 * it + 2);
            __builtin_amdgcn_sched_barrier(0);
            if (it < 7) {
                int f0 = (2 * it + 3) * 64;
                xb000 = *(const float4*)(xrow[0] + f0);
                xb001 = *(const float4*)(xrow[0] + f0 + 4);
                xb010 = *(const float4*)(xrow[0] + f0 + 32);
                xb011 = *(const float4*)(xrow[0] + f0 + 36);
                xb100 = *(const float4*)(xrow[1] + f0);
                xb101 = *(const float4*)(xrow[1] + f0 + 4);
                xb110 = *(const float4*)(xrow[1] + f0 + 32);
                xb111 = *(const float4*)(xrow[1] + f0 + 36);
            }
            MF2(buf, 0, av00, av10);
            MF2(buf, 1, av01, av11);
        }
        if (it < 7) {
            asm volatile("s_waitcnt vmcnt(8) lgkmcnt(0)" ::: "memory");
            __builtin_amdgcn_s_barrier();
            buf ^= 1;
        }
    }

#pragma unroll
    for (int sub = 0; sub < 2; sub++) {
#pragma unroll
        for (int ct = 0; ct < 6; ct++) {
            int gc = (wc * 6 + ct) * 16;
            int proj = gc >> 7;
            int dcol = gc & 127;
            if (proj < 2) {
                u16* dst = proj ? k : q;
#pragma unroll
                for (int j = 0; j < 4; j++) {
                    int row = mrow0 + wr * 32 + sub * 16 + g * 4 + j;
                    dst[(size_t)row * D_ + dcol + c] = f2bf(acc[sub][ct][j]);
                }
            } else {
                int srow = mrow0 + wr * 32 + sub * 16 + g * 4;
                int b = srow >> 12;
                int s = srow & 4095;
                ushort4 pk;
                pk.x = f2bf(acc[sub][ct][0]);
                pk.y = f2bf(acc[sub][ct][1]);
                pk.z = f2bf(acc[sub][ct][2]);
                pk.w = f2bf(acc[sub][ct][3]);
                *(ushort4*)(vT + ((size_t)(b * D_ + dcol + c)) * S_ + s) = pk;
            }
        }
    }
}

// ---------------------------------------------------------------------------
// Kernel 2: flash attention, SWAPPED 32x32 (r22, 69.5us) + numerics-safe
// chain thinning: max3-tree row max (exact), fma exp-arg, pairwise rs-sum
// tree, persistent stage pointers (+=const per round), sched_barrier(0)
// after in-loop STAGE to pin VMEM issue early.
// ---------------------------------------------------------------------------
__global__ __launch_bounds__(512, 2) void attn_kernel(const u16* __restrict__ q,
                                                      const u16* __restrict__ k,
                                                      const u16* __restrict__ vT,
                                                      float* __restrict__ out) {
    // bijective XCD-chunk swizzle (nwg=256, 8 XCDs, chunk=32)
    int bid = blockIdx.x;
    int sw = (bid & 7) * 32 + (bid >> 3);
    const int b = sw >> 6;          // batch 0..3 (2 XCDs per batch)
    const int qt = sw & 63;         // q-tile 0..63 (64 rows)
    const int wv = threadIdx.x >> 6;    // 0..7
    const int qs = wv >> 2;             // q-sub 0..1 (32 rows)
    const int grp = wv & 3;             // kv group: tiles t*4+grp
    const int l = threadIdx.x & 63;
    const int l31 = l & 31;
    const int hi = l >> 5;
    const int qrow = qt * 64 + qs * 32 + l31;   // this lane's q (within batch)

    __shared__ __align__(16) char smem[134400];
    char* gbase = smem + grp * 32768;

    const char* kbb = (const char*)(k + (size_t)b * S_ * D_);
    const char* vbb = (const char*)(vT + (size_t)b * D_ * S_);

    // Q B-frags: B[k=e][col=q]; lane: q=qrow, e = ek*16 + hi*8 + j
    bf16x8 aq[8];
    const u16* qp = q + (size_t)(b * S_ + qrow) * D_ + hi * 8;
#pragma unroll
    for (int ek = 0; ek < 8; ek++) aq[ek] = *(const bf16x8*)(qp + ek * 16);

    f32x16 o[4] = {};   // o[dt][r] = O^T[d=dt*32+crow(r,hi)][q=qrow]
    float m = -1e30f, ll = 0.0f;   // ll: partial (own crow half)

    // persistent stage pointers, advanced by constants each STAGE
    const char* kp_[4];
    const char* vp_[4];
#pragma unroll
    for (int ii = 0; ii < 4; ii++) {
        int i = qs * 4 + ii;
        int rowk = i * 4 + (l >> 4);               // 0..31
        int colk = (l & 15) * 16;
        kp_[ii] = kbb + (size_t)(grp * 32 + rowk) * 256 + (colk ^ ((rowk & 7) << 4));
        int rowv = i * 16 + (l >> 2);              // 0..127
        int colv = (l & 3) * 16;
        vp_[ii] = vbb + (size_t)rowv * 8192 + (size_t)(grp * 32) * 2
                + (colv ^ ((rowv & 3) << 4));
    }

    auto STAGE = [&](int buf) {
        char* dst = gbase + buf * 16384;
#pragma unroll
        for (int ii = 0; ii < 4; ii++)
            gload16(kp_[ii], dst + (qs * 4 + ii) * 1024);
#pragma unroll
        for (int ii = 0; ii < 4; ii++)
            gload16(vp_[ii], dst + 8192 + (qs * 4 + ii) * 1024);
#pragma unroll
        for (int ii = 0; ii < 4; ii++) {
            kp_[ii] += 128 * 256;                  // +128 kv rows
            vp_[ii] += 128 * 2;                    // +128 kv cols (bytes)
        }
    };

    STAGE(0);
    __syncthreads();                 // drains vmcnt: buf0 ready

    const float LOG2E = 1.44269504f;
    int buf = 0;
    for (int t = 0; t < 32; t++) {
        if (t < 31) {
            STAGE(buf ^ 1);
            __builtin_amdgcn_sched_barrier(0);     // pin VMEM issue early
        }

        const char* kbuf = gbase + buf * 16384;
        const char* vbuf = kbuf + 8192;

        // ---- S^T = K Q^T : 8 x mfma 32x32x16 over e ----
        f32x16 s = {};
        __builtin_amdgcn_s_setprio(1);
#pragma unroll
        for (int ek = 0; ek < 8; ek++) {
            u16x8 kr = *(const u16x8*)(kbuf + l31 * 256
                       + ((ek * 32 + hi * 16) ^ ((l31 & 7) << 4)));
            s = __builtin_amdgcn_mfma_f32_32x32x16_bf16(
                    __builtin_bit_cast(bf16x8, kr), aq[ek], s, 0, 0, 0);
        }
        __builtin_amdgcn_s_setprio(0);

        // ---- in-register softmax: max3-tree (exact) + partner swap ----
        float a0 = fmaxf(fmaxf(s[0], s[1]), s[2]);
        float a1 = fmaxf(fmaxf(s[3], s[4]), s[5]);
        float a2 = fmaxf(fmaxf(s[6], s[7]), s[8]);
        float a3 = fmaxf(fmaxf(s[9], s[10]), s[11]);
        float a4 = fmaxf(fmaxf(s[12], s[13]), s[14]);
        float b0 = fmaxf(fmaxf(a0, a1), a2);
        float b1 = fmaxf(fmaxf(a3, a4), s[15]);
        float tilemax = partner_max(fmaxf(b0, b1));
        bool need = tilemax > m + 8.0f;
        if (__any(need)) {
            float mn = fmaxf(m, tilemax);
            float alpha = exp2f((m - mn) * LOG2E);
            ll *= alpha;
#pragma unroll
            for (int dt = 0; dt < 4; dt++)
#pragma unroll
                for (int r = 0; r < 16; r++) o[dt][r] *= alpha;
            m = mn;
        }
        const float nmc = -m * LOG2E;              // exp arg = fma(s, log2e, nmc)
        float p[16];
#pragma unroll
        for (int r = 0; r < 16; r++)
            p[r] = exp2f(fmaf(s[r], LOG2E, nmc));
        {   // pairwise sum tree, depth 4
            float s0 = (p[0] + p[1]) + (p[2] + p[3]);
            float s1 = (p[4] + p[5]) + (p[6] + p[7]);
            float s2 = (p[8] + p[9]) + (p[10] + p[11]);
            float s3 = (p[12] + p[13]) + (p[14] + p[15]);
            ll += (s0 + s1) + (s2 + s3);
        }

        // ---- pack P^T frags: 8 packs + 4 permlane32_swap ----
        u32 c0 = cvtpk(p[0], p[1]),  c1 = cvtpk(p[2], p[3]);
        u32 c2 = cvtpk(p[4], p[5]),  c3 = cvtpk(p[6], p[7]);
        u32 c4 = cvtpk(p[8], p[9]),  c5 = cvtpk(p[10], p[11]);
        u32 c6 = cvtpk(p[12], p[13]), c7 = cvtpk(p[14], p[15]);
        { u32x2 r = plswap2(c0, c2); c0 = r[0]; c2 = r[1]; }
        { u32x2 r = plswap2(c1, c3); c1 = r[0]; c3 = r[1]; }
        { u32x2 r = plswap2(c4, c6); c4 = r[0]; c6 = r[1]; }
        { u32x2 r = plswap2(c5, c7); c5 = r[0]; c7 = r[1]; }
        u32x4 f0v = {c0, c1, c2, c3};
        u32x4 f1v = {c4, c5, c6, c7};
        bf16x8 pb0 = __builtin_bit_cast(bf16x8, f0v);
        bf16x8 pb1 = __builtin_bit_cast(bf16x8, f1v);

        // ---- PV: o[dt] += V^T_frag x P^T_frag (2 kv-halves x 4 d-tiles) ----
        __builtin_amdgcn_s_setprio(1);
#pragma unroll
        for (int dt = 0; dt < 4; dt++) {
            int row = dt * 32 + l31;
            int swzv = (row & 3) << 4;
            u16x8 v0 = *(const u16x8*)(vbuf + row * 64 + ((hi * 16) ^ swzv));
            o[dt] = __builtin_amdgcn_mfma_f32_32x32x16_bf16(
                        __builtin_bit_cast(bf16x8, v0), pb0, o[dt], 0, 0, 0);
            u16x8 v1 = *(const u16x8*)(vbuf + row * 64 + ((32 + hi * 16) ^ swzv));
            o[dt] = __builtin_amdgcn_mfma_f32_32x32x16_bf16(
                        __builtin_bit_cast(bf16x8, v1), pb1, o[dt], 0, 0, 0);
        }
        __builtin_amdgcn_s_setprio(0);

        __syncthreads();    // drain staging vmcnt + round barrier
        buf ^= 1;
    }

    // ---- epilogue: transpose via LDS overlay + 4-way merge ----
    float llF = partner_sum(ll);    // combine the two kv-halves
    __syncthreads();                // kv bufs done; begin overlay
    float* co = (float*)smem;                 // [grp*64+q][129]
    float* cm = (float*)(smem + 132096);      // [4][64]
    float* cl = cm + 256;
    const int qloc = qs * 32 + l31;
#pragma unroll
    for (int dt = 0; dt < 4; dt++)
#pragma unroll
        for (int r = 0; r < 16; r++) {
            int d = dt * 32 + (r & 3) + 8 * (r >> 2) + 4 * hi;
            co[(size_t)(grp * 64 + qloc) * 129 + d] = o[dt][r];
        }
    cm[grp * 64 + qloc] = m;        // lanes l, l^32 write same value
    cl[grp * 64 + qloc] = llF;
    __syncthreads();

    {   // final: thread -> (q = tid>>3, 16 d at (tid&7)*16)
        int qq = (int)threadIdx.x >> 3;
        int dbase = ((int)threadIdx.x & 7) * 16;
        float M = cm[qq];
#pragma unroll
        for (int gi = 1; gi < 4; gi++) M = fmaxf(M, cm[gi * 64 + qq]);
        float eg[4];
        float L = 0.f;
#pragma unroll
        for (int gi = 0; gi < 4; gi++) {
            eg[gi] = exp2f((cm[gi * 64 + qq] - M) * 1.44269504f);
            L += cl[gi * 64 + qq] * eg[gi];
        }
        float rL = 1.0f / L;
        float* op = out + (size_t)(b * S_ + qt * 64 + qq) * D_ + dbase;
#pragma unroll
        for (int dd = 0; dd < 16; dd += 4) {
            float4 res;
#pragma unroll
            for (int i = 0; i < 4; i++) {
                float a = 0.f;
#pragma unroll
                for (int gi = 0; gi < 4; gi++)
                    a += co[(size_t)(gi * 64 + qq) * 129 + dbase + dd + i] * eg[gi];
                (&res.x)[i] = a * rL;
            }
            *(float4*)(op + dd) = res;
        }
    }
}

extern "C" void kernel_launch(void* const* d_in, const int* in_sizes, int n_in,
                              void* d_out, int out_size, void* d_ws, size_t ws_size,
                              hipStream_t stream) {
    const float* x  = (const float*)d_in[0];
    const float* Wq = (const float*)d_in[1];
    const float* Wk = (const float*)d_in[2];
    const float* Wv = (const float*)d_in[3];
    float* out = (float*)d_out;   // reference output dtype is float32

    // workspace layout (bytes): q 4MB | k 4MB | vT 4MB | Wt2 768KB
    u16* q  = (u16*)d_ws;
    u16* k  = q  + (size_t)B_ * S_ * D_;
    u16* vT = k  + (size_t)B_ * S_ * D_;
    u16* Wt = vT + (size_t)B_ * S_ * D_;

    wt_kernel<<<(3 * 32 * 8 * 64) / 256, 256, 0, stream>>>(Wq, Wk, Wv, Wt);
    qkv_fused<<<(B_ * S_) / 64, 512, 0, stream>>>(x, Wt, q, k, vT);
    attn_kernel<<<(B_ * S_) / 64, 512, 0, stream>>>(q, k, vT, out);
}